// Round 15
// baseline (487.311 us; speedup 1.0000x reference)
//
#include <hip/hip_runtime.h>
#include <cstdint>
#include <cstddef>

// VQ-VAE vector quantizer forward, MI355X.
// B=65536 rows, K=4096 codes, D=256.
// Outputs (flat float32): z_q_st[B*D] | vq_loss | perplexity | indices[B] | diversity_loss

#define NROWS     65536
#define NCODES    4096
#define DDIM      256
#define CAND_CAP  24
#define ZSCALE    2.8853900817779268f   // 2*log2(e): v = ZSCALE*z.e - log2e*||e||^2
#define EECOEF    1.4426950408889634f   // log2(e)
#define VMARGIN   2.8853900817779268f   // d-space margin 2.0
#define VSKIP     24.525815695112378f   // d-space skip 17 (dropped soft terms < e^-17, Z>=1)

typedef _Float16 half8 __attribute__((ext_vector_type(8)));
typedef _Float16 half4 __attribute__((ext_vector_type(4)));
typedef float    f32x16 __attribute__((ext_vector_type(16)));

// ---- workspace layout (bytes) ----
#define WS_BINCNT   0u          // 4096*4    = 16384    (zeroed)
#define WS_ZERO_END 16384u
#define WS_CANDCNT  16384u      // 65536*4   = 262144   (plain-written by sweep, no zero)
#define WS_SPART    278528u     // 512*4096*4 = 8388608 (fully written by sweep)
#define WS_EF16     8667136u    // 4096*256*2 = 2097152
#define WS_EE       10764288u   // 4096*4     = 16384
#define WS_ROWD     10780672u   // 65536*4    = 262144
#define WS_CANDIDX  11042816u   // 65536*24*4 = 6291456 (aliased as tm[4096] dbl after refine)
#define WS_TE       17334272u   // 4096*8     = 32768
#define WS_TP       17367040u   // 4096*8     = 32768
#define WS_END      17399808u

__device__ __forceinline__ void gload_lds16(const void* g, void* lds) {
    __builtin_amdgcn_global_load_lds(
        (const __attribute__((address_space(1))) unsigned int*)g,
        (__attribute__((address_space(3))) unsigned int*)lds, 16, 0, 0);
}

// ---------------- prep (embedding only): fp32 -> fp16 copy + row norms ----------------
__global__ __launch_bounds__(256)
void prep_kernel(const float* __restrict__ src, _Float16* __restrict__ dst,
                 float* __restrict__ norms)
{
    const int tid = threadIdx.x;
    const int w = tid >> 6, l = tid & 63;
    const int row = blockIdx.x * 4 + w;
    const float4 v = *(const float4*)(src + (size_t)row * DDIM + l * 4);
    half4 h;
    h[0] = (_Float16)v.x; h[1] = (_Float16)v.y;
    h[2] = (_Float16)v.z; h[3] = (_Float16)v.w;
    *(half4*)(dst + (size_t)row * DDIM + l * 4) = h;
    double s = (double)v.x * v.x + (double)v.y * v.y
             + (double)v.z * v.z + (double)v.w * v.w;
#pragma unroll
    for (int off = 1; off < 64; off <<= 1) s += __shfl_xor(s, off, 64);
    if (l == 0) norms[row] = (float)s;
}

// ---------------- fused two-phase distance sweep, 32x32x16 MFMA ----------------
// r12 structure: 4 waves, wave w owns rows w*32..+31 for ALL codes; B: 64-code x
// K=256 sub-tiles, 2 x 32 KB LDS dbuf, FRAGMENT-MAJOR lane-linear (conflict-free
// ds_read_b128; staged via global_load_lds with pre-permuted per-lane source).
// NEW: v_mfma_f32_32x32x16_f16 — 32 MFMAs/step (was 64) at the better 32x32 rate
// (2382 vs 2075 TF µbench) and half the MFMA issue slots.  Fragments:
//   A: row = l&31, k = q*16 + (l>>5)*8 + i       (af[q], q = 0..15, half8)
//   B: col = l&31, k = q*16 + (l>>5)*8 + i       (LDS slot fid = q*2+c)
//   C: col = c*32 + (l&31), row = (reg&3)+8*(reg>>2)+4*(l>>5)   [m74/m101]
// exp2-domain: z pre-scaled by 2*log2e at fp16 conversion, acc init =
// -log2e*||e||^2, so soft = exp2(v - mv)/Z with bare v_exp_f32 (no mul).
// eev one step ahead; ballot candidates (32-lane row groups); NO setprio.
// Phase 0 (s 0..63): exact online (max v, Z), defer-rescale, skip-far exp2.
// Phase 1 (s 64..127): v bitwise identical (same init + chain); soft into Sl;
// candidate shortlist (true argmin always a hit; fp64 refine resolves).
__global__ __launch_bounds__(256, 2)
void sweep_fused_kernel(const float* __restrict__ z, const _Float16* __restrict__ ef,
                        const float* __restrict__ ee, float* __restrict__ Spart,
                        int* __restrict__ cand_cnt, int* __restrict__ cand_idx)
{
    __shared__ _Float16 Bl[2][64 * 256];   // 2 x 32 KB, fragment-major
    __shared__ float Sl[NCODES];           // 16 KB soft accumulator

    const int tid = threadIdx.x;
    const int w = tid >> 6, l = tid & 63;
    const int c31 = l & 31, lh = l >> 5;
    const int row0 = blockIdx.x * 128;
    const int rowb = row0 + w * 32;

    // A fragments (pre-scaled by ZSCALE): af[q] = z'[rowb + c31][q*16 + lh*8 .. +8]
    half8 af[16];
#pragma unroll
    for (int q = 0; q < 16; ++q) {
        const float* zp = z + (size_t)(rowb + c31) * DDIM + q * 16 + lh * 8;
        const float4 v0 = *(const float4*)zp;
        const float4 v1 = *(const float4*)(zp + 4);
        half8 h;
        h[0] = (_Float16)(v0.x * ZSCALE); h[1] = (_Float16)(v0.y * ZSCALE);
        h[2] = (_Float16)(v0.z * ZSCALE); h[3] = (_Float16)(v0.w * ZSCALE);
        h[4] = (_Float16)(v1.x * ZSCALE); h[5] = (_Float16)(v1.y * ZSCALE);
        h[6] = (_Float16)(v1.z * ZSCALE); h[7] = (_Float16)(v1.w * ZSCALE);
        af[q] = h;
    }

    for (int i = tid; i < NCODES; i += 256) Sl[i] = 0.0f;

    // staging: instr it_g = w*8+it = slot fid (q = fid>>1, c = fid&1); lane l
    // fetches global code c*32+c31 at kbytes q*32+lh*16 -> LDS fid*1024 + l*16.
    int soff[8];
#pragma unroll
    for (int it = 0; it < 8; ++it) {
        const int fid = w * 8 + it;
        const int q = fid >> 1, c = fid & 1;
        soff[it] = (c * 32 + c31) * 512 + q * 32 + lh * 16;
    }
    const char* efb = (const char*)ef;
    char* blb = (char*)&Bl[0][0];

    float pmx[16], pZ[16];
#pragma unroll
    for (int i = 0; i < 16; ++i) { pmx[i] = -1e30f; pZ[i] = 0.0f; }
    int bcnt[16];
#pragma unroll
    for (int i = 0; i < 16; ++i) bcnt[i] = 0;

    // prologue: eev for tile 0 + stage tile 0 into buffer 0
    float eevc[2], eevn[2];
#pragma unroll
    for (int c = 0; c < 2; ++c) eevc[c] = ee[c * 32 + c31];
#pragma unroll
    for (int it = 0; it < 8; ++it)
        gload_lds16(efb + soff[it], blb + (w * 8 + it) * 1024);
    __syncthreads();

    for (int s = 0; s < 128; ++s) {
        const int cur = s & 1;
        const int nt = s & 63;
        const int nnt = (s + 1) & 63;

        // next-step eev: issued now, consumed after the barrier (never waited mid-loop)
#pragma unroll
        for (int c = 0; c < 2; ++c) eevn[c] = ee[nnt * 64 + c * 32 + c31];

        if (s < 127) {                      // stage next sub-tile into other buffer
            const char* src = efb + ((size_t)nnt << 15);
            char* dst = blb + (cur ^ 1) * 32768;
#pragma unroll
            for (int it = 0; it < 8; ++it)
                gload_lds16(src + soff[it], dst + (w * 8 + it) * 1024);
        }

        // acc init: -log2e*||e||^2  ->  MFMA output v = ZSCALE*z.e - log2e*||e||^2
        const float ehA = -EECOEF * eevc[0], ehB = -EECOEF * eevc[1];
        f32x16 accA, accB;
#pragma unroll
        for (int j = 0; j < 16; ++j) { accA[j] = ehA; accB[j] = ehB; }

        // lane-linear B reads (conflict-free), immediate offsets; 32 MFMAs
        const char* bb = blb + cur * 32768 + (l << 4);
#pragma unroll
        for (int q = 0; q < 16; ++q) {
            const half8 b0 = *(const half8*)(bb + (q * 2 + 0) * 1024);
            const half8 b1 = *(const half8*)(bb + (q * 2 + 1) * 1024);
            accA = __builtin_amdgcn_mfma_f32_32x32x16_f16(af[q], b0, accA, 0, 0, 0);
            accB = __builtin_amdgcn_mfma_f32_32x32x16_f16(af[q], b1, accB, 0, 0, 0);
        }

        if (s < 64) {
            // phase 0: exact online (max v, Z); rescale only on improve; skip far pairs
#pragma unroll
            for (int r = 0; r < 16; ++r) {
                const float u0 = accA[r];
                const float u1 = accB[r];
                const float mloc = fmaxf(u0, u1);
                float m = pmx[r];
                if (mloc > m - VSKIP) {   // dropped terms < e^-17, Z >= 1
                    if (mloc > m) { pZ[r] *= exp2f(m - mloc); m = mloc; pmx[r] = m; }
                    pZ[r] += exp2f(u0 - m) + exp2f(u1 - m);
                }
            }
        } else {
            // phase 1: v bitwise identical to phase 0 (same init, same MFMA chain)
            float sp[2] = {0.f, 0.f};
#pragma unroll
            for (int r = 0; r < 16; ++r) {
                const float m = pmx[r], iz = pZ[r];   // pZ holds 1/Z in phase 1
                const float u0 = accA[r];
                const float u1 = accB[r];
                // candidates: ballot + prefix-popcount within the 32-lane row group
#pragma unroll
                for (int c = 0; c < 2; ++c) {
                    const float u = (c == 0) ? u0 : u1;
                    const bool hit = (u >= m - VMARGIN);   // m = exact phase-0 row max
                    const unsigned long long mk = __ballot(hit);
                    if (mk) {                              // uniform branch, rare
                        const unsigned grp = (unsigned)(mk >> (lh * 32));
                        const int slot = bcnt[r] + __popc(grp & ((1u << c31) - 1u));
                        if (hit && slot < CAND_CAP) {
                            const int rg_ = rowb + (r & 3) + 8 * (r >> 2) + 4 * lh;
                            cand_idx[(size_t)rg_ * CAND_CAP + slot] = nt * 64 + c * 32 + c31;
                        }
                        bcnt[r] += __popc(grp);
                    }
                }
                // soft partials: one pair-max guard (dropped terms < e^-17, Z >= 1)
                if (fmaxf(u0, u1) >= m - VSKIP) {
                    sp[0] += exp2f(u0 - m) * iz;
                    sp[1] += exp2f(u1 - m) * iz;
                }
            }
            // per-code sum across the two half-wave row sets, then LDS accumulate
#pragma unroll
            for (int c = 0; c < 2; ++c) {
                float v = sp[c];
                v += __shfl_xor(v, 32, 64);
                if (lh == 0) atomicAdd(&Sl[nt * 64 + c * 32 + c31], v);
            }
        }

        if (s == 63) {
            // phase boundary: merge (max,Z) across the 32 lanes sharing each row; pZ := 1/Z
#pragma unroll
            for (int r = 0; r < 16; ++r) {
                float m = pmx[r], Zv = pZ[r];
#pragma unroll
                for (int off = 1; off < 32; off <<= 1) {
                    const float mo = __shfl_xor(m, off, 64);
                    const float Zo = __shfl_xor(Zv, off, 64);
                    const float mn = fmaxf(m, mo);
                    Zv = Zv * exp2f(m - mn) + Zo * exp2f(mo - mn);
                    m = mn;
                }
                pmx[r] = m;
                pZ[r] = 1.0f / Zv;
            }
        }

        __syncthreads();   // sole vmcnt drain: staging + eev issued a full phase ago
        eevc[0] = eevn[0]; eevc[1] = eevn[1];
    }

    // final: per-row candidate counts (plain stores; every row covered once)
    if (c31 == 0) {
#pragma unroll
        for (int r = 0; r < 16; ++r)
            cand_cnt[rowb + (r & 3) + 8 * (r >> 2) + 4 * lh] = bcnt[r];
    }

    for (int i = tid; i < NCODES; i += 256)
        Spart[(size_t)blockIdx.x * NCODES + i] = Sl[i];
}

// ---------------- refine: exact fp64 argmin over candidates ----------------
__global__ __launch_bounds__(256)
void refine_kernel(const float* __restrict__ z, const float* __restrict__ emb,
                   const int* __restrict__ cand_cnt, const int* __restrict__ cand_idx,
                   float* __restrict__ out_zq, float* __restrict__ out_idx,
                   unsigned int* __restrict__ bincnt, float* __restrict__ rowD)
{
    const int tid = threadIdx.x;
    const int w = tid >> 6, l = tid & 63;
    const int row = blockIdx.x * 4 + w;
    const float4 zv = *(const float4*)(z + (size_t)row * DDIM + l * 4);
    const double z0 = zv.x, z1 = zv.y, z2 = zv.z, z3 = zv.w;
    const int craw = cand_cnt[row];
    const int cnt = craw < 1 ? 1 : (craw > CAND_CAP ? CAND_CAP : craw);
    double dmin = 1e300; int kmin = 0;
    for (int c = 0; c < cnt; ++c) {
        int k = (craw < 1) ? 0 : cand_idx[(size_t)row * CAND_CAP + c];
        k &= (NCODES - 1);
        const float4 ev = *(const float4*)(emb + (size_t)k * DDIM + l * 4);
        const double t0 = z0 - ev.x, t1 = z1 - ev.y, t2 = z2 - ev.z, t3 = z3 - ev.w;
        double s = t0 * t0 + t1 * t1 + t2 * t2 + t3 * t3;
#pragma unroll
        for (int off = 1; off < 64; off <<= 1) s += __shfl_xor(s, off, 64);
        if (s < dmin || (s == dmin && k < kmin)) { dmin = s; kmin = k; }
    }
    const float4 bv = *(const float4*)(emb + (size_t)kmin * DDIM + l * 4);
    *(float4*)(out_zq + (size_t)row * DDIM + l * 4) = bv;   // z + sg(zq - z) == zq
    if (l == 0) {
        out_idx[row] = (float)kmin;
        atomicAdd(&bincnt[kmin], 1u);
        rowD[row] = (float)dmin;                             // dmin == ||z - zq||^2
    }
}

// ---------------- reductions ----------------
__global__ __launch_bounds__(256)
void reduce1_kernel(const float* __restrict__ Spart, const unsigned int* __restrict__ bincnt,
                    const float* __restrict__ rowD,
                    double* __restrict__ te, double* __restrict__ tp, double* __restrict__ tm)
{
    const int k = blockIdx.x * 256 + threadIdx.x;   // grid 16 -> k < 4096
    double s = 0.0;
#pragma unroll 8
    for (int wg = 0; wg < 512; ++wg) s += (double)Spart[(size_t)wg * NCODES + k];
    const double avg = s * (1.0 / 65536.0);
    te[k] = avg * log(avg + 1e-10);
    const double ap = (double)bincnt[k] * (1.0 / 65536.0);
    tp[k] = ap * log(ap + 1e-10);
    double dm = 0.0;
#pragma unroll
    for (int j = 0; j < 16; ++j) dm += (double)rowD[k * 16 + j];
    tm[k] = dm;
}

__global__ __launch_bounds__(256)
void reduce2_kernel(const double* __restrict__ te, const double* __restrict__ tp,
                    const double* __restrict__ tm, float* __restrict__ out)
{
    __shared__ double sa[256], sb[256], sc[256];
    const int tid = threadIdx.x;
    double a = 0.0, b = 0.0, c = 0.0;
    for (int i = tid; i < NCODES; i += 256) { a += te[i]; b += tp[i]; c += tm[i]; }
    sa[tid] = a; sb[tid] = b; sc[tid] = c;
    __syncthreads();
    for (int s = 128; s > 0; s >>= 1) {
        if (tid < s) { sa[tid] += sa[tid + s]; sb[tid] += sb[tid + s]; sc[tid] += sc[tid + s]; }
        __syncthreads();
    }
    if (tid == 0) {
        const double entropy    = -sa[0];
        const double diversity  = log(4096.0) - entropy;
        const double perplexity = exp(-sb[0]);
        const double mse        = sc[0] * (1.0 / 16777216.0);
        const double vq         = 1.25 * mse + 0.1 * diversity;  // 0.25*c + e + 0.1*d, c==e
        out[16777216] = (float)vq;
        out[16777217] = (float)perplexity;
        out[16842754] = (float)diversity;
    }
}

extern "C" void kernel_launch(void* const* d_in, const int* in_sizes, int n_in,
                              void* d_out, int out_size, void* d_ws, size_t ws_size,
                              hipStream_t stream)
{
    const float* z   = (const float*)d_in[0];
    const float* emb = (const float*)d_in[1];
    float* out = (float*)d_out;
    char* ws = (char*)d_ws;
    if (ws_size < (size_t)WS_END) return;   // need ~17.4 MB scratch

    unsigned int* bincnt   = (unsigned int*)(ws + WS_BINCNT);
    int*          cand_cnt = (int*)(ws + WS_CANDCNT);
    float*        Spart    = (float*)(ws + WS_SPART);
    _Float16*     ef16     = (_Float16*)(ws + WS_EF16);
    float*        ee       = (float*)(ws + WS_EE);
    float*        rowD     = (float*)(ws + WS_ROWD);
    int*          cand_idx = (int*)(ws + WS_CANDIDX);
    double*       te       = (double*)(ws + WS_TE);
    double*       tp       = (double*)(ws + WS_TP);
    double*       tm       = (double*)(ws + WS_CANDIDX);  // cand_idx dead after refine

    hipMemsetAsync(d_ws, 0, WS_ZERO_END, stream);   // bincnt only (16 KB)
    hipLaunchKernelGGL(prep_kernel, dim3(NCODES / 4), dim3(256), 0, stream, emb, ef16, ee);
    hipLaunchKernelGGL(sweep_fused_kernel, dim3(NROWS / 128), dim3(256), 0, stream,
                       z, ef16, ee, Spart, cand_cnt, cand_idx);
    hipLaunchKernelGGL(refine_kernel, dim3(NROWS / 4), dim3(256), 0, stream,
                       z, emb, cand_cnt, cand_idx, out, out + 16777218, bincnt, rowD);
    hipLaunchKernelGGL(reduce1_kernel, dim3(16), dim3(256), 0, stream, Spart, bincnt, rowD, te, tp, tm);
    hipLaunchKernelGGL(reduce2_kernel, dim3(1), dim3(256), 0, stream, te, tp, tm, out);
}